// Round 1
// baseline (349.433 us; speedup 1.0000x reference)
//
#include <hip/hip_runtime.h>
#include <stdint.h>

typedef unsigned short u16;
typedef __bf16 bf16x8 __attribute__((ext_vector_type(8)));
typedef float f32x4 __attribute__((ext_vector_type(4)));

#define DIN 4096
#define DOUT 4096
#define BB 4096
#define KR 256
#define RK 2048  // 2*L*K

__device__ __forceinline__ u16 f2bf(float f) {
    union { float f; unsigned u; } v; v.f = f;
    unsigned r = v.u + 0x7FFFu + ((v.u >> 16) & 1u);
    return (u16)(r >> 16);
}

__device__ __forceinline__ void gl_lds16(const void* g, void* l) {
    __builtin_amdgcn_global_load_lds((const __attribute__((address_space(1))) void*)g,
                                     (__attribute__((address_space(3))) void*)l,
                                     16, 0, 0);
}

// ---- convert f32 -> bf16, 8 elements/thread ----
__global__ __launch_bounds__(256) void cvt_f32_bf16(const float* __restrict__ src,
                                                    u16* __restrict__ dst, int n8) {
    int i = blockIdx.x * blockDim.x + threadIdx.x;
    if (i >= n8) return;
    const float4* s = reinterpret_cast<const float4*>(src) + (size_t)i * 2;
    float4 a = s[0], b = s[1];
    uint4 o;
    o.x = f2bf(a.x) | ((unsigned)f2bf(a.y) << 16);
    o.y = f2bf(a.z) | ((unsigned)f2bf(a.w) << 16);
    o.z = f2bf(b.x) | ((unsigned)f2bf(b.y) << 16);
    o.w = f2bf(b.z) | ((unsigned)f2bf(b.w) << 16);
    reinterpret_cast<uint4*>(dst)[i] = o;
}

// ---- pack W1[d][r] = (br? U2s : S1s)[l][d][k], r = l*512 + br*256 + k ----
__global__ __launch_bounds__(256) void pack_w1(const float* __restrict__ S1s,
                                               const float* __restrict__ U2s,
                                               u16* __restrict__ W1) {
    int idx = blockIdx.x * blockDim.x + threadIdx.x;  // DIN*RK/8 total
    int k8 = idx & 31;
    int br = (idx >> 5) & 1;
    int l  = (idx >> 6) & 3;
    int d  = idx >> 8;
    const float* src = (br ? U2s : S1s) + ((size_t)(l * DIN + d) * KR + k8 * 8);
    float4 a = reinterpret_cast<const float4*>(src)[0];
    float4 b = reinterpret_cast<const float4*>(src)[1];
    uint4 o;
    o.x = f2bf(a.x) | ((unsigned)f2bf(a.y) << 16);
    o.y = f2bf(a.z) | ((unsigned)f2bf(a.w) << 16);
    o.z = f2bf(b.x) | ((unsigned)f2bf(b.y) << 16);
    o.w = f2bf(b.z) | ((unsigned)f2bf(b.w) << 16);
    *reinterpret_cast<uint4*>(W1 + (size_t)d * RK + l * 512 + br * 256 + k8 * 8) = o;
}

// ---- pack W2T[o][r] = (br? S2s : U1s)[l][k][o], via 64x64 LDS transpose ----
__global__ __launch_bounds__(256) void pack_w2t(const float* __restrict__ U1s,
                                                const float* __restrict__ S2s,
                                                u16* __restrict__ W2T) {
    __shared__ u16 lds[64][68];
    int b  = blockIdx.x;
    int bo = b & 63;          // o-tile (Dout/64)
    int bk = (b >> 6) & 3;    // k-tile (KR/64)
    int lb = b >> 8;          // 0..7
    int l = lb >> 1, br = lb & 1;
    const float* src = (br ? S2s : U1s) + (size_t)l * KR * DOUT;
    int t = threadIdx.x;
    int o0 = bo * 64, k0 = bk * 64;
    #pragma unroll
    for (int p = 0; p < 4; ++p) {
        int kl = p * 16 + (t >> 4);
        int ol = (t & 15) * 4;
        float4 v = *reinterpret_cast<const float4*>(src + (size_t)(k0 + kl) * DOUT + o0 + ol);
        ushort4 pk;
        pk.x = f2bf(v.x); pk.y = f2bf(v.y); pk.z = f2bf(v.z); pk.w = f2bf(v.w);
        *reinterpret_cast<ushort4*>(&lds[kl][ol]) = pk;
    }
    __syncthreads();
    #pragma unroll
    for (int p = 0; p < 2; ++p) {
        int ol = p * 32 + (t >> 3);
        int k8 = t & 7;
        u16 tmp[8];
        #pragma unroll
        for (int j = 0; j < 8; ++j) tmp[j] = lds[k8 * 8 + j][ol];
        uint4 o;
        o.x = tmp[0] | ((unsigned)tmp[1] << 16);
        o.y = tmp[2] | ((unsigned)tmp[3] << 16);
        o.z = tmp[4] | ((unsigned)tmp[5] << 16);
        o.w = tmp[6] | ((unsigned)tmp[7] << 16);
        *reinterpret_cast<uint4*>(W2T + (size_t)(o0 + ol) * RK + l * 512 + br * 256 + k0 + k8 * 8) = o;
    }
}

// ---- gemm_bt: C[M][N] = A[M][Kd] * Bt[N][Kd]^T, bf16 in, m97-style 128x128 ----
// EPI=0: store bf16. EPI=1: store f32 (acc + bias[c]) * 0.125
template <int EPI>
__global__ __launch_bounds__(256) void gemm_bt(const u16* __restrict__ A,
                                               const u16* __restrict__ Bt,
                                               void* __restrict__ Cv,
                                               const float* __restrict__ bias,
                                               int M, int N, int Kd) {
    __shared__ u16 la[128 * 32];
    __shared__ u16 lb[128 * 32];
    const int t = threadIdx.x;
    const int lane = t & 63;
    const int w = t >> 6;
    const int wr = w >> 1;
    const int wc = w & 1;
    const int m0 = blockIdx.y * 128;
    const int n0 = blockIdx.x * 128;

    f32x4 acc[4][4] = {};

    const int sr = t >> 2;          // 0..63 staged row
    const int sc = (t & 3) * 8;     // k-chunk within BK=32
    const u16* ga = A + (size_t)(m0 + sr) * Kd + sc;
    const u16* gb = Bt + (size_t)(n0 + sr) * Kd + sc;
    const size_t rstep = (size_t)64 * Kd;
    u16* lag = la + t * 8;          // t*16 bytes (linear wave-uniform layout)
    u16* lbg = lb + t * 8;

    const int row = lane & 15;
    const int g8 = (lane >> 4) * 8;

    for (int kt = 0; kt < Kd; kt += 32) {
        gl_lds16(ga + kt, lag);
        gl_lds16(ga + kt + rstep, lag + 2048);
        gl_lds16(gb + kt, lbg);
        gl_lds16(gb + kt + rstep, lbg + 2048);
        __syncthreads();

        bf16x8 af[4], bfv[4];
        #pragma unroll
        for (int i = 0; i < 4; ++i)
            af[i] = *reinterpret_cast<const bf16x8*>(&la[(wr * 64 + i * 16 + row) * 32 + g8]);
        #pragma unroll
        for (int i = 0; i < 4; ++i)
            bfv[i] = *reinterpret_cast<const bf16x8*>(&lb[(wc * 64 + i * 16 + row) * 32 + g8]);
        #pragma unroll
        for (int mi = 0; mi < 4; ++mi)
            #pragma unroll
            for (int ni = 0; ni < 4; ++ni)
                acc[mi][ni] = __builtin_amdgcn_mfma_f32_16x16x32_bf16(af[mi], bfv[ni], acc[mi][ni], 0, 0, 0);
        __syncthreads();
    }

    const int col = lane & 15;
    const int rb = (lane >> 4) * 4;
    if (EPI == 0) {
        u16* Cb = (u16*)Cv;
        #pragma unroll
        for (int mi = 0; mi < 4; ++mi)
            #pragma unroll
            for (int ni = 0; ni < 4; ++ni) {
                int c = n0 + wc * 64 + ni * 16 + col;
                #pragma unroll
                for (int j = 0; j < 4; ++j) {
                    int r = m0 + wr * 64 + mi * 16 + rb + j;
                    Cb[(size_t)r * N + c] = f2bf(acc[mi][ni][j]);
                }
            }
    } else {
        float* Cf = (float*)Cv;
        #pragma unroll
        for (int mi = 0; mi < 4; ++mi)
            #pragma unroll
            for (int ni = 0; ni < 4; ++ni) {
                int c = n0 + wc * 64 + ni * 16 + col;
                float bv = bias[c];
                #pragma unroll
                for (int j = 0; j < 4; ++j) {
                    int r = m0 + wr * 64 + mi * 16 + rb + j;
                    Cf[(size_t)r * N + c] = (acc[mi][ni][j] + bv) * 0.125f;
                }
            }
    }
}

extern "C" void kernel_launch(void* const* d_in, const int* in_sizes, int n_in,
                              void* d_out, int out_size, void* d_ws, size_t ws_size,
                              hipStream_t stream) {
    const float* hin  = (const float*)d_in[0];
    const float* S1s  = (const float*)d_in[1];
    const float* S2s  = (const float*)d_in[2];
    const float* U1s  = (const float*)d_in[3];
    const float* U2s  = (const float*)d_in[4];
    const float* bias = (const float*)d_in[5];
    float* out = (float*)d_out;

    // ws layout: [WT: 32MB][shared region: 32MB -> W1(16MB)+W2T(16MB), later hin_bf]
    const size_t SZ_WT = (size_t)DOUT * DIN * 2;      // 33.5 MB
    const size_t SZ_W1 = (size_t)DIN * RK * 2;        // 16.8 MB
    if (ws_size < SZ_WT + 2 * SZ_W1) return;          // fail loudly (zeros) rather than corrupt
    u16* WTbf  = (u16*)d_ws;
    u16* W1bf  = (u16*)((char*)d_ws + SZ_WT);
    u16* W2Tbf = (u16*)((char*)d_ws + SZ_WT + SZ_W1);
    u16* hinbf = (u16*)((char*)d_ws + SZ_WT);         // reuses W1/W2T region

    // 1) pack weights
    pack_w1<<<(DIN * RK / 8) / 256, 256, 0, stream>>>(S1s, U2s, W1bf);
    pack_w2t<<<64 * 4 * 8, 256, 0, stream>>>(U1s, S2s, W2Tbf);
    // 2) WT[o][d] = sum_r W2T[o][r] * W1[d][r]
    gemm_bt<0><<<dim3(DIN / 128, DOUT / 128), 256, 0, stream>>>(W2Tbf, W1bf, WTbf, nullptr, DOUT, DIN, RK);
    // 3) hin -> bf16 (overwrites W1/W2T region, no longer needed)
    cvt_f32_bf16<<<(BB * DIN / 8) / 256, 256, 0, stream>>>(hin, hinbf, BB * DIN / 8);
    // 4) out[b][o] = (sum_d hin[b][d] * WT[o][d] + bias[o]) * 0.125
    gemm_bt<1><<<dim3(DOUT / 128, BB / 128), 256, 0, stream>>>(hinbf, WTbf, out, bias, BB, DOUT, DIN);
}

// Round 2
// 248.426 us; speedup vs baseline: 1.4066x; 1.4066x over previous
//
#include <hip/hip_runtime.h>
#include <stdint.h>

typedef unsigned short u16;
typedef __bf16 bf16x8 __attribute__((ext_vector_type(8)));
typedef float f32x4 __attribute__((ext_vector_type(4)));

#define DIN 4096
#define DOUT 4096
#define BB 4096
#define KR 256
#define RK 2048  // 2*L*K

__device__ __forceinline__ u16 f2bf(float f) {
    union { float f; unsigned u; } v; v.f = f;
    unsigned r = v.u + 0x7FFFu + ((v.u >> 16) & 1u);
    return (u16)(r >> 16);
}

__device__ __forceinline__ void gl_lds16(const void* g, void* l) {
    __builtin_amdgcn_global_load_lds((const __attribute__((address_space(1))) void*)g,
                                     (__attribute__((address_space(3))) void*)l,
                                     16, 0, 0);
}

// ---- convert f32 -> bf16, 8 elements/thread ----
__global__ __launch_bounds__(256) void cvt_f32_bf16(const float* __restrict__ src,
                                                    u16* __restrict__ dst, int n8) {
    int i = blockIdx.x * blockDim.x + threadIdx.x;
    if (i >= n8) return;
    const float4* s = reinterpret_cast<const float4*>(src) + (size_t)i * 2;
    float4 a = s[0], b = s[1];
    uint4 o;
    o.x = f2bf(a.x) | ((unsigned)f2bf(a.y) << 16);
    o.y = f2bf(a.z) | ((unsigned)f2bf(a.w) << 16);
    o.z = f2bf(b.x) | ((unsigned)f2bf(b.y) << 16);
    o.w = f2bf(b.z) | ((unsigned)f2bf(b.w) << 16);
    reinterpret_cast<uint4*>(dst)[i] = o;
}

// ---- pack W1T[r][d] = (br? U2s : S1s)[l][d][k], r = l*512 + br*256 + k ----
// transpose [d][k] -> [k][d] per (l,br) slab via 64x64 LDS tile
__global__ __launch_bounds__(256) void pack_w1t(const float* __restrict__ S1s,
                                                const float* __restrict__ U2s,
                                                u16* __restrict__ W1T) {
    __shared__ u16 lds[64][68];
    int b  = blockIdx.x;
    int bd = b & 63;          // d-tile (Din/64)
    int bk = (b >> 6) & 3;    // k-tile (KR/64)
    int lb = b >> 8;          // 0..7
    int l = lb >> 1, br = lb & 1;
    const float* src = (br ? U2s : S1s) + (size_t)l * DIN * KR;
    int t = threadIdx.x;
    int d0 = bd * 64, k0 = bk * 64;
    int r0 = l * 512 + br * 256 + k0;
    #pragma unroll
    for (int p = 0; p < 4; ++p) {
        int dl = p * 16 + (t >> 4);
        int kc = (t & 15) * 4;
        float4 v = *reinterpret_cast<const float4*>(src + (size_t)(d0 + dl) * KR + k0 + kc);
        ushort4 pk;
        pk.x = f2bf(v.x); pk.y = f2bf(v.y); pk.z = f2bf(v.z); pk.w = f2bf(v.w);
        *reinterpret_cast<ushort4*>(&lds[dl][kc]) = pk;
    }
    __syncthreads();
    #pragma unroll
    for (int p = 0; p < 2; ++p) {
        int kl = p * 32 + (t >> 3);
        int d8 = t & 7;
        u16 tmp[8];
        #pragma unroll
        for (int j = 0; j < 8; ++j) tmp[j] = lds[d8 * 8 + j][kl];
        uint4 o;
        o.x = tmp[0] | ((unsigned)tmp[1] << 16);
        o.y = tmp[2] | ((unsigned)tmp[3] << 16);
        o.z = tmp[4] | ((unsigned)tmp[5] << 16);
        o.w = tmp[6] | ((unsigned)tmp[7] << 16);
        *reinterpret_cast<uint4*>(W1T + (size_t)(r0 + kl) * DIN + d0 + d8 * 8) = o;
    }
}

// ---- pack W2T[o][r] = (br? S2s : U1s)[l][k][o], via 64x64 LDS transpose ----
__global__ __launch_bounds__(256) void pack_w2t(const float* __restrict__ U1s,
                                                const float* __restrict__ S2s,
                                                u16* __restrict__ W2T) {
    __shared__ u16 lds[64][68];
    int b  = blockIdx.x;
    int bo = b & 63;          // o-tile (Dout/64)
    int bk = (b >> 6) & 3;    // k-tile (KR/64)
    int lb = b >> 8;          // 0..7
    int l = lb >> 1, br = lb & 1;
    const float* src = (br ? S2s : U1s) + (size_t)l * KR * DOUT;
    int t = threadIdx.x;
    int o0 = bo * 64, k0 = bk * 64;
    #pragma unroll
    for (int p = 0; p < 4; ++p) {
        int kl = p * 16 + (t >> 4);
        int ol = (t & 15) * 4;
        float4 v = *reinterpret_cast<const float4*>(src + (size_t)(k0 + kl) * DOUT + o0 + ol);
        ushort4 pk;
        pk.x = f2bf(v.x); pk.y = f2bf(v.y); pk.z = f2bf(v.z); pk.w = f2bf(v.w);
        *reinterpret_cast<ushort4*>(&lds[kl][ol]) = pk;
    }
    __syncthreads();
    #pragma unroll
    for (int p = 0; p < 2; ++p) {
        int ol = p * 32 + (t >> 3);
        int k8 = t & 7;
        u16 tmp[8];
        #pragma unroll
        for (int j = 0; j < 8; ++j) tmp[j] = lds[k8 * 8 + j][ol];
        uint4 o;
        o.x = tmp[0] | ((unsigned)tmp[1] << 16);
        o.y = tmp[2] | ((unsigned)tmp[3] << 16);
        o.z = tmp[4] | ((unsigned)tmp[5] << 16);
        o.w = tmp[6] | ((unsigned)tmp[7] << 16);
        *reinterpret_cast<uint4*>(W2T + (size_t)(o0 + ol) * RK + l * 512 + br * 256 + k0 + k8 * 8) = o;
    }
}

// ---- gemm_bt: C[M][N] = A[M][Kd] * Bt[N][Kd]^T, bf16 in, m97-style 128x128 ----
// EPI=0: store bf16. EPI=1: store f32 (acc + bias[c]) * 0.125
template <int EPI>
__global__ __launch_bounds__(256) void gemm_bt(const u16* __restrict__ A,
                                               const u16* __restrict__ Bt,
                                               void* __restrict__ Cv,
                                               const float* __restrict__ bias,
                                               int M, int N, int Kd) {
    __shared__ u16 la[128 * 32];
    __shared__ u16 lb[128 * 32];
    const int t = threadIdx.x;
    const int lane = t & 63;
    const int w = t >> 6;
    const int wr = w >> 1;
    const int wc = w & 1;

    // bijective XCD-aware swizzle (nwg % 8 == 0 for all our launches)
    const int gx = gridDim.x;
    int bid = blockIdx.y * gx + blockIdx.x;
    const int cpx = (gx * gridDim.y) >> 3;
    bid = (bid & 7) * cpx + (bid >> 3);
    const int m0 = (bid / gx) * 128;
    const int n0 = (bid % gx) * 128;

    f32x4 acc[4][4] = {};

    const int sr = t >> 2;          // 0..63 staged row
    const int sc = (t & 3) * 8;     // k-chunk within BK=32
    const u16* ga = A + (size_t)(m0 + sr) * Kd + sc;
    const u16* gb = Bt + (size_t)(n0 + sr) * Kd + sc;
    const size_t rstep = (size_t)64 * Kd;
    u16* lag = la + t * 8;          // t*16 bytes (linear wave-uniform layout)
    u16* lbg = lb + t * 8;

    const int row = lane & 15;
    const int g8 = (lane >> 4) * 8;

    for (int kt = 0; kt < Kd; kt += 32) {
        gl_lds16(ga + kt, lag);
        gl_lds16(ga + kt + rstep, lag + 2048);
        gl_lds16(gb + kt, lbg);
        gl_lds16(gb + kt + rstep, lbg + 2048);
        __syncthreads();

        bf16x8 af[4], bfv[4];
        #pragma unroll
        for (int i = 0; i < 4; ++i)
            af[i] = *reinterpret_cast<const bf16x8*>(&la[(wr * 64 + i * 16 + row) * 32 + g8]);
        #pragma unroll
        for (int i = 0; i < 4; ++i)
            bfv[i] = *reinterpret_cast<const bf16x8*>(&lb[(wc * 64 + i * 16 + row) * 32 + g8]);
        #pragma unroll
        for (int mi = 0; mi < 4; ++mi)
            #pragma unroll
            for (int ni = 0; ni < 4; ++ni)
                acc[mi][ni] = __builtin_amdgcn_mfma_f32_16x16x32_bf16(af[mi], bfv[ni], acc[mi][ni], 0, 0, 0);
        __syncthreads();
    }

    const int col = lane & 15;
    const int rb = (lane >> 4) * 4;
    if (EPI == 0) {
        u16* Cb = (u16*)Cv;
        #pragma unroll
        for (int mi = 0; mi < 4; ++mi)
            #pragma unroll
            for (int ni = 0; ni < 4; ++ni) {
                int c = n0 + wc * 64 + ni * 16 + col;
                #pragma unroll
                for (int j = 0; j < 4; ++j) {
                    int r = m0 + wr * 64 + mi * 16 + rb + j;
                    Cb[(size_t)r * N + c] = f2bf(acc[mi][ni][j]);
                }
            }
    } else {
        float* Cf = (float*)Cv;
        #pragma unroll
        for (int mi = 0; mi < 4; ++mi)
            #pragma unroll
            for (int ni = 0; ni < 4; ++ni) {
                int c = n0 + wc * 64 + ni * 16 + col;
                float bv = bias[c];
                #pragma unroll
                for (int j = 0; j < 4; ++j) {
                    int r = m0 + wr * 64 + mi * 16 + rb + j;
                    Cf[(size_t)r * N + c] = (acc[mi][ni][j] + bv) * 0.125f;
                }
            }
    }
}

extern "C" void kernel_launch(void* const* d_in, const int* in_sizes, int n_in,
                              void* d_out, int out_size, void* d_ws, size_t ws_size,
                              hipStream_t stream) {
    const float* hin  = (const float*)d_in[0];
    const float* S1s  = (const float*)d_in[1];
    const float* S2s  = (const float*)d_in[2];
    const float* U1s  = (const float*)d_in[3];
    const float* U2s  = (const float*)d_in[4];
    const float* bias = (const float*)d_in[5];
    float* out = (float*)d_out;

    // ws layout: [hinbf 33.5MB][Wx 16.8MB (W1T, later W2T)][a 16.8MB]  = 67.1MB peak
    const size_t SZ_HIN = (size_t)BB * DIN * 2;
    const size_t SZ_W   = (size_t)RK * DIN * 2;
    if (ws_size < SZ_HIN + 2 * SZ_W) return;
    u16* hinbf = (u16*)d_ws;
    u16* Wx    = (u16*)((char*)d_ws + SZ_HIN);        // W1T for gemm1, then W2T for gemm2
    u16* abf   = (u16*)((char*)d_ws + SZ_HIN + SZ_W);

    // 1) pack W1T [RK][DIN], convert hin -> bf16
    pack_w1t<<<64 * 4 * 8, 256, 0, stream>>>(S1s, U2s, Wx);
    cvt_f32_bf16<<<(BB * DIN / 8) / 256, 256, 0, stream>>>(hin, hinbf, BB * DIN / 8);
    // 2) a[b][r] = sum_d hin[b][d] * W1T[r][d]   (M=BB, N=RK, K=DIN)
    gemm_bt<0><<<dim3(RK / 128, BB / 128), 256, 0, stream>>>(hinbf, Wx, abf, nullptr, BB, RK, DIN);
    // 3) pack W2T [DOUT][RK] (reuses W1T region; stream-ordered after gemm1)
    pack_w2t<<<64 * 4 * 8, 256, 0, stream>>>(U1s, S2s, Wx);
    // 4) out[b][o] = (sum_r a[b][r] * W2T[o][r] + bias[o]) * 0.125  (M=BB, N=DOUT, K=RK)
    gemm_bt<1><<<dim3(DOUT / 128, BB / 128), 256, 0, stream>>>(abf, Wx, out, bias, BB, DOUT, RK);
}

// Round 4
// 188.999 us; speedup vs baseline: 1.8489x; 1.3144x over previous
//
#include <hip/hip_runtime.h>
#include <stdint.h>

typedef unsigned short u16;
typedef __bf16 bf16x8 __attribute__((ext_vector_type(8)));
typedef float f32x4 __attribute__((ext_vector_type(4)));

#define DIN 4096
#define DOUT 4096
#define BB 4096
#define KR 256
#define RK 2048  // 2*L*K

__device__ __forceinline__ u16 f2bf(float f) {
    union { float f; unsigned u; } v; v.f = f;
    unsigned r = v.u + 0x7FFFu + ((v.u >> 16) & 1u);
    return (u16)(r >> 16);
}

__device__ __forceinline__ void gl_lds16(const void* g, void* l) {
    __builtin_amdgcn_global_load_lds((const __attribute__((address_space(1))) void*)g,
                                     (__attribute__((address_space(3))) void*)l,
                                     16, 0, 0);
}

// ---- convert f32 -> bf16, 8 elements/thread ----
__global__ __launch_bounds__(256) void cvt_f32_bf16(const float* __restrict__ src,
                                                    u16* __restrict__ dst, int n8) {
    int i = blockIdx.x * blockDim.x + threadIdx.x;
    if (i >= n8) return;
    const float4* s = reinterpret_cast<const float4*>(src) + (size_t)i * 2;
    float4 a = s[0], b = s[1];
    uint4 o;
    o.x = f2bf(a.x) | ((unsigned)f2bf(a.y) << 16);
    o.y = f2bf(a.z) | ((unsigned)f2bf(a.w) << 16);
    o.z = f2bf(b.x) | ((unsigned)f2bf(b.y) << 16);
    o.w = f2bf(b.z) | ((unsigned)f2bf(b.w) << 16);
    reinterpret_cast<uint4*>(dst)[i] = o;
}

// ---- pack W1T[r][d] = (br? U2s : S1s)[l][d][k], r = l*512 + br*256 + k ----
__global__ __launch_bounds__(256) void pack_w1t(const float* __restrict__ S1s,
                                                const float* __restrict__ U2s,
                                                u16* __restrict__ W1T) {
    __shared__ u16 lds[64][68];
    int b  = blockIdx.x;
    int bd = b & 63;
    int bk = (b >> 6) & 3;
    int lb = b >> 8;
    int l = lb >> 1, br = lb & 1;
    const float* src = (br ? U2s : S1s) + (size_t)l * DIN * KR;
    int t = threadIdx.x;
    int d0 = bd * 64, k0 = bk * 64;
    int r0 = l * 512 + br * 256 + k0;
    #pragma unroll
    for (int p = 0; p < 4; ++p) {
        int dl = p * 16 + (t >> 4);
        int kc = (t & 15) * 4;
        float4 v = *reinterpret_cast<const float4*>(src + (size_t)(d0 + dl) * KR + k0 + kc);
        ushort4 pk;
        pk.x = f2bf(v.x); pk.y = f2bf(v.y); pk.z = f2bf(v.z); pk.w = f2bf(v.w);
        *reinterpret_cast<ushort4*>(&lds[dl][kc]) = pk;
    }
    __syncthreads();
    #pragma unroll
    for (int p = 0; p < 2; ++p) {
        int kl = p * 32 + (t >> 3);
        int d8 = t & 7;
        u16 tmp[8];
        #pragma unroll
        for (int j = 0; j < 8; ++j) tmp[j] = lds[d8 * 8 + j][kl];
        uint4 o;
        o.x = tmp[0] | ((unsigned)tmp[1] << 16);
        o.y = tmp[2] | ((unsigned)tmp[3] << 16);
        o.z = tmp[4] | ((unsigned)tmp[5] << 16);
        o.w = tmp[6] | ((unsigned)tmp[7] << 16);
        *reinterpret_cast<uint4*>(W1T + (size_t)(r0 + kl) * DIN + d0 + d8 * 8) = o;
    }
}

// ---- pack W2T[o][r] = (br? S2s : U1s)[l][k][o] ----
__global__ __launch_bounds__(256) void pack_w2t(const float* __restrict__ U1s,
                                                const float* __restrict__ S2s,
                                                u16* __restrict__ W2T) {
    __shared__ u16 lds[64][68];
    int b  = blockIdx.x;
    int bo = b & 63;
    int bk = (b >> 6) & 3;
    int lb = b >> 8;
    int l = lb >> 1, br = lb & 1;
    const float* src = (br ? S2s : U1s) + (size_t)l * KR * DOUT;
    int t = threadIdx.x;
    int o0 = bo * 64, k0 = bk * 64;
    #pragma unroll
    for (int p = 0; p < 4; ++p) {
        int kl = p * 16 + (t >> 4);
        int ol = (t & 15) * 4;
        float4 v = *reinterpret_cast<const float4*>(src + (size_t)(k0 + kl) * DOUT + o0 + ol);
        ushort4 pk;
        pk.x = f2bf(v.x); pk.y = f2bf(v.y); pk.z = f2bf(v.z); pk.w = f2bf(v.w);
        *reinterpret_cast<ushort4*>(&lds[kl][ol]) = pk;
    }
    __syncthreads();
    #pragma unroll
    for (int p = 0; p < 2; ++p) {
        int ol = p * 32 + (t >> 3);
        int k8 = t & 7;
        u16 tmp[8];
        #pragma unroll
        for (int j = 0; j < 8; ++j) tmp[j] = lds[k8 * 8 + j][ol];
        uint4 o;
        o.x = tmp[0] | ((unsigned)tmp[1] << 16);
        o.y = tmp[2] | ((unsigned)tmp[3] << 16);
        o.z = tmp[4] | ((unsigned)tmp[5] << 16);
        o.w = tmp[6] | ((unsigned)tmp[7] << 16);
        *reinterpret_cast<uint4*>(W2T + (size_t)(o0 + ol) * RK + l * 512 + br * 256 + k0 + k8 * 8) = o;
    }
}

// ==== 8-phase 256xBN GEMM: C[M][N] = A[M][Kd] * Bt[N][Kd]^T ====
// BM=256, BK=64, 8 waves (2Mx4N), 512 threads. 2 K-tiles/iter, 8 phases.
// LDS: A 2buf x 2half x [128][64] bf16 (64KB); B 2buf x 2half x [BN/2][64].
// XOR swizzle: byte ^= ((row&7)<<4); pre-applied to per-lane global src
// (gl_lds dest stays linear), applied again on ds_read side.
// vmcnt(4|3) only at phases 4 and 8 (counted, never drained in-loop).
template <int BN, int EPI>
__global__ __launch_bounds__(512) void gemm8(const u16* __restrict__ A,
                                             const u16* __restrict__ Bt,
                                             void* __restrict__ Cv,
                                             const float* __restrict__ bias,
                                             int N, int Kd) {
    extern __shared__ char smem[];
    constexpr int BHB = (BN == 256) ? 16384 : 8192;  // B half bytes
    constexpr int BROWS = BN / 2;                    // B half rows
    constexpr int NF = BN / 128;                     // n-frags per wave per phase
    char* ldsA = smem;                // 4 halves * 16KB
    char* ldsB = smem + 65536;        // 4 halves * BHB

    const int tid = threadIdx.x;
    const int l = tid & 63;
    const int wv = tid >> 6;
    const int wr = wv >> 2;          // 0..1
    const int wc = wv & 3;           // 0..3

    int bid = blockIdx.x;            // 256 blocks always
    bid = (bid & 7) * 32 + (bid >> 3);   // bijective XCD swizzle (256%8==0)
    const int mt = bid >> 4, nt = bid & 15;
    const int m0 = mt * 256, n0 = nt * BN;

    const int NITER = Kd >> 7;

    // staging per-thread source offsets (swizzle pre-applied to global src)
    size_t aoff[2], boff[2];
    {
        #pragma unroll
        for (int r = 0; r < 2; ++r) {
            int lin = (r * 512 + tid) * 16;
            int s = lin ^ (((lin >> 7) & 7) << 4);
            int e = s >> 1;
            size_t o = (size_t)(e >> 6) * Kd + (e & 63);
            aoff[r] = (size_t)m0 * Kd + o;
            boff[r] = (size_t)n0 * Kd + o;
        }
    }

    auto issueA = [&](int h, int b, size_t kb) {
        char* d = ldsA + (((b << 1) | h) * 16384) + tid * 16;
        gl_lds16(A + aoff[0] + (size_t)h * 128 * Kd + kb, d);
        gl_lds16(A + aoff[1] + (size_t)h * 128 * Kd + kb, d + 8192);
    };
    auto issueB = [&](int h, int b, size_t kb) {
        char* d = ldsB + (((b << 1) | h) * BHB) + tid * 16;
        gl_lds16(Bt + boff[0] + (size_t)h * BROWS * Kd + kb, d);
        if constexpr (BN == 256)
            gl_lds16(Bt + boff[1] + (size_t)h * BROWS * Kd + kb, d + 8192);
    };

    // LDS read constants: addr = row*128 | cc, cc = ((l>>4)^(l&7))<<4; ks=1: ^64
    int rowAb[4];
    #pragma unroll
    for (int m = 0; m < 4; ++m) rowAb[m] = (wr * 64 + m * 16 + (l & 15)) * 128;
    int rowBb[NF];
    #pragma unroll
    for (int n = 0; n < NF; ++n)
        rowBb[n] = ((BN == 256 ? wc * 32 : wc * 16) + n * 16 + (l & 15)) * 128;
    const int cc0 = ((l >> 4) ^ (l & 7)) << 4;

    f32x4 acc[2][2][4][NF] = {};

#define PHASE(BUF, MH, NH, ISSUE_STMT, VM) do {                                   \
    bf16x8 af_[4][2]; bf16x8 bq_[NF][2];                                          \
    const char* Ah_ = ldsA + (((BUF) << 1) | (MH)) * 16384;                       \
    const char* Bh_ = ldsB + (((BUF) << 1) | (NH)) * BHB;                         \
    _Pragma("unroll") for (int m_ = 0; m_ < 4; ++m_) {                            \
        af_[m_][0] = *(const bf16x8*)(Ah_ + (rowAb[m_] | cc0));                   \
        af_[m_][1] = *(const bf16x8*)(Ah_ + ((rowAb[m_] | cc0) ^ 64)); }          \
    _Pragma("unroll") for (int n_ = 0; n_ < NF; ++n_) {                           \
        bq_[n_][0] = *(const bf16x8*)(Bh_ + (rowBb[n_] | cc0));                   \
        bq_[n_][1] = *(const bf16x8*)(Bh_ + ((rowBb[n_] | cc0) ^ 64)); }          \
    ISSUE_STMT;                                                                   \
    __builtin_amdgcn_s_barrier();                                                 \
    asm volatile("s_waitcnt lgkmcnt(0)" ::: "memory");                            \
    __builtin_amdgcn_s_setprio(1);                                                \
    _Pragma("unroll") for (int m_ = 0; m_ < 4; ++m_)                              \
        _Pragma("unroll") for (int n_ = 0; n_ < NF; ++n_) {                       \
            acc[MH][NH][m_][n_] = __builtin_amdgcn_mfma_f32_16x16x32_bf16(        \
                af_[m_][0], bq_[n_][0], acc[MH][NH][m_][n_], 0, 0, 0);            \
            acc[MH][NH][m_][n_] = __builtin_amdgcn_mfma_f32_16x16x32_bf16(        \
                af_[m_][1], bq_[n_][1], acc[MH][NH][m_][n_], 0, 0, 0); }          \
    __builtin_amdgcn_s_setprio(0);                                                \
    if (VM) { if (BN == 256) asm volatile("s_waitcnt vmcnt(4)" ::: "memory");     \
              else           asm volatile("s_waitcnt vmcnt(3)" ::: "memory"); }   \
    __builtin_amdgcn_s_barrier();                                                 \
} while (0)

    // prologue: tile0 all 4 halves + tile1 {A0,B0}; keep tile1 pair in flight
    issueA(0, 0, 0);  issueB(0, 0, 0);
    issueA(1, 0, 0);  issueB(1, 0, 0);
    issueA(0, 1, 64); issueB(0, 1, 64);
    if (BN == 256) asm volatile("s_waitcnt vmcnt(4)" ::: "memory");
    else           asm volatile("s_waitcnt vmcnt(3)" ::: "memory");
    __builtin_amdgcn_s_barrier();

    for (int J = 0; J < NITER; ++J) {
        const size_t kc = (size_t)J << 7;
        PHASE(0, 0, 0, issueA(1, 1, kc + 64),  0);
        PHASE(0, 0, 1, issueB(1, 1, kc + 64),  0);
        PHASE(0, 1, 0, issueA(0, 0, kc + 128), 0);
        PHASE(0, 1, 1, issueB(0, 0, kc + 128), 1);
        PHASE(1, 0, 0, issueA(1, 0, kc + 128), 0);
        PHASE(1, 0, 1, issueB(1, 0, kc + 128), 0);
        PHASE(1, 1, 0, issueA(0, 1, kc + 192), 0);
        PHASE(1, 1, 1, issueB(0, 1, kc + 192), 1);
    }
#undef PHASE

    const int colc = l & 15, rb = (l >> 4) * 4;
    #pragma unroll
    for (int mh = 0; mh < 2; ++mh)
    #pragma unroll
    for (int nh = 0; nh < 2; ++nh)
    #pragma unroll
    for (int m = 0; m < 4; ++m)
    #pragma unroll
    for (int n = 0; n < NF; ++n) {
        int c = n0 + nh * (BN / 2) + wc * (BN / 8) + n * 16 + colc;
        int r0r = m0 + mh * 128 + wr * 64 + m * 16 + rb;
        if (EPI == 0) {
            u16* Cb = (u16*)Cv;
            #pragma unroll
            for (int j = 0; j < 4; ++j)
                Cb[(size_t)(r0r + j) * N + c] = f2bf(acc[mh][nh][m][n][j]);
        } else {
            float* Cf = (float*)Cv;
            float bv = bias[c];
            #pragma unroll
            for (int j = 0; j < 4; ++j)
                Cf[(size_t)(r0r + j) * N + c] = (acc[mh][nh][m][n][j] + bv) * 0.125f;
        }
    }
}

extern "C" void kernel_launch(void* const* d_in, const int* in_sizes, int n_in,
                              void* d_out, int out_size, void* d_ws, size_t ws_size,
                              hipStream_t stream) {
    const float* hin  = (const float*)d_in[0];
    const float* S1s  = (const float*)d_in[1];
    const float* S2s  = (const float*)d_in[2];
    const float* U1s  = (const float*)d_in[3];
    const float* U2s  = (const float*)d_in[4];
    const float* bias = (const float*)d_in[5];
    float* out = (float*)d_out;

    // ws: [hinbf][Wx (W1T then W2T)][abf], each padded 512B for the last
    // iteration's prefetch overread (<=256B past the K extent).
    const size_t SZ_HIN = (size_t)BB * DIN * 2 + 512;
    const size_t SZ_W   = (size_t)RK * DIN * 2 + 512;
    const size_t SZ_A   = (size_t)BB * RK * 2 + 512;
    if (ws_size < SZ_HIN + SZ_W + SZ_A) return;
    u16* hinbf = (u16*)d_ws;
    u16* Wx    = (u16*)((char*)d_ws + SZ_HIN);
    u16* abf   = (u16*)((char*)d_ws + SZ_HIN + SZ_W);

    (void)hipFuncSetAttribute(reinterpret_cast<const void*>(&gemm8<128, 0>),
                              hipFuncAttributeMaxDynamicSharedMemorySize, 98304);
    (void)hipFuncSetAttribute(reinterpret_cast<const void*>(&gemm8<256, 1>),
                              hipFuncAttributeMaxDynamicSharedMemorySize, 131072);

    // 1) pack W1T [RK][DIN]; hin -> bf16
    pack_w1t<<<64 * 4 * 8, 256, 0, stream>>>(S1s, U2s, Wx);
    cvt_f32_bf16<<<(BB * DIN / 8) / 256, 256, 0, stream>>>(hin, hinbf, BB * DIN / 8);
    // 2) a[b][r] = sum_d hin[b][d] * W1T[r][d]   (M=4096, N=2048, K=4096)
    gemm8<128, 0><<<256, 512, 98304, stream>>>(hinbf, Wx, abf, nullptr, RK, DIN);
    // 3) pack W2T [DOUT][RK] (reuses Wx after gemm1)
    pack_w2t<<<64 * 4 * 8, 256, 0, stream>>>(U1s, S2s, Wx);
    // 4) out = (a @ W2T^T + bias) / 8   (M=4096, N=4096, K=2048)
    gemm8<256, 1><<<256, 512, 131072, stream>>>(abf, Wx, out, bias, DOUT, RK);
}

// Round 5
// 169.148 us; speedup vs baseline: 2.0658x; 1.1174x over previous
//
#include <hip/hip_runtime.h>
#include <stdint.h>

typedef unsigned short u16;
typedef __bf16 bf16x8 __attribute__((ext_vector_type(8)));
typedef float f32x4 __attribute__((ext_vector_type(4)));

#define DIN 4096
#define DOUT 4096
#define BB 4096
#define KR 256
#define RK 2048  // 2*L*K

__device__ __forceinline__ u16 f2bf(float f) {
    union { float f; unsigned u; } v; v.f = f;
    unsigned r = v.u + 0x7FFFu + ((v.u >> 16) & 1u);
    return (u16)(r >> 16);
}

__device__ __forceinline__ void gl_lds16(const void* g, void* l) {
    __builtin_amdgcn_global_load_lds((const __attribute__((address_space(1))) void*)g,
                                     (__attribute__((address_space(3))) void*)l,
                                     16, 0, 0);
}

// ---- convert f32 -> bf16, 8 elements/thread ----
__global__ __launch_bounds__(256) void cvt_f32_bf16(const float* __restrict__ src,
                                                    u16* __restrict__ dst, int n8) {
    int i = blockIdx.x * blockDim.x + threadIdx.x;
    if (i >= n8) return;
    const float4* s = reinterpret_cast<const float4*>(src) + (size_t)i * 2;
    float4 a = s[0], b = s[1];
    uint4 o;
    o.x = f2bf(a.x) | ((unsigned)f2bf(a.y) << 16);
    o.y = f2bf(a.z) | ((unsigned)f2bf(a.w) << 16);
    o.z = f2bf(b.x) | ((unsigned)f2bf(b.y) << 16);
    o.w = f2bf(b.z) | ((unsigned)f2bf(b.w) << 16);
    reinterpret_cast<uint4*>(dst)[i] = o;
}

// ---- pack W1T[r][d] = (br? U2s : S1s)[l][d][k], r = l*512 + br*256 + k ----
__global__ __launch_bounds__(256) void pack_w1t(const float* __restrict__ S1s,
                                                const float* __restrict__ U2s,
                                                u16* __restrict__ W1T) {
    __shared__ u16 lds[64][68];
    int b  = blockIdx.x;
    int bd = b & 63;
    int bk = (b >> 6) & 3;
    int lb = b >> 8;
    int l = lb >> 1, br = lb & 1;
    const float* src = (br ? U2s : S1s) + (size_t)l * DIN * KR;
    int t = threadIdx.x;
    int d0 = bd * 64, k0 = bk * 64;
    int r0 = l * 512 + br * 256 + k0;
    #pragma unroll
    for (int p = 0; p < 4; ++p) {
        int dl = p * 16 + (t >> 4);
        int kc = (t & 15) * 4;
        float4 v = *reinterpret_cast<const float4*>(src + (size_t)(d0 + dl) * KR + k0 + kc);
        ushort4 pk;
        pk.x = f2bf(v.x); pk.y = f2bf(v.y); pk.z = f2bf(v.z); pk.w = f2bf(v.w);
        *reinterpret_cast<ushort4*>(&lds[dl][kc]) = pk;
    }
    __syncthreads();
    #pragma unroll
    for (int p = 0; p < 2; ++p) {
        int kl = p * 32 + (t >> 3);
        int d8 = t & 7;
        u16 tmp[8];
        #pragma unroll
        for (int j = 0; j < 8; ++j) tmp[j] = lds[d8 * 8 + j][kl];
        uint4 o;
        o.x = tmp[0] | ((unsigned)tmp[1] << 16);
        o.y = tmp[2] | ((unsigned)tmp[3] << 16);
        o.z = tmp[4] | ((unsigned)tmp[5] << 16);
        o.w = tmp[6] | ((unsigned)tmp[7] << 16);
        *reinterpret_cast<uint4*>(W1T + (size_t)(r0 + kl) * DIN + d0 + d8 * 8) = o;
    }
}

// ---- pack W2T[o][r] = (br? S2s : U1s)[l][k][o] ----
__global__ __launch_bounds__(256) void pack_w2t(const float* __restrict__ U1s,
                                                const float* __restrict__ S2s,
                                                u16* __restrict__ W2T) {
    __shared__ u16 lds[64][68];
    int b  = blockIdx.x;
    int bo = b & 63;
    int bk = (b >> 6) & 3;
    int lb = b >> 8;
    int l = lb >> 1, br = lb & 1;
    const float* src = (br ? S2s : U1s) + (size_t)l * KR * DOUT;
    int t = threadIdx.x;
    int o0 = bo * 64, k0 = bk * 64;
    #pragma unroll
    for (int p = 0; p < 4; ++p) {
        int kl = p * 16 + (t >> 4);
        int ol = (t & 15) * 4;
        float4 v = *reinterpret_cast<const float4*>(src + (size_t)(k0 + kl) * DOUT + o0 + ol);
        ushort4 pk;
        pk.x = f2bf(v.x); pk.y = f2bf(v.y); pk.z = f2bf(v.z); pk.w = f2bf(v.w);
        *reinterpret_cast<ushort4*>(&lds[kl][ol]) = pk;
    }
    __syncthreads();
    #pragma unroll
    for (int p = 0; p < 2; ++p) {
        int ol = p * 32 + (t >> 3);
        int k8 = t & 7;
        u16 tmp[8];
        #pragma unroll
        for (int j = 0; j < 8; ++j) tmp[j] = lds[k8 * 8 + j][ol];
        uint4 o;
        o.x = tmp[0] | ((unsigned)tmp[1] << 16);
        o.y = tmp[2] | ((unsigned)tmp[3] << 16);
        o.z = tmp[4] | ((unsigned)tmp[5] << 16);
        o.w = tmp[6] | ((unsigned)tmp[7] << 16);
        *reinterpret_cast<uint4*>(W2T + (size_t)(o0 + ol) * RK + l * 512 + br * 256 + k0 + k8 * 8) = o;
    }
}

// ==== 8-phase 256xBN GEMM: C[M][N] = A[M][Kd] * Bt[N][Kd]^T ====
// BM=256, BK=64, 8 waves (MW x NW), 512 threads. 2 K-tiles/iter, 8 phases.
// Register-frag reuse: per K-tile phase order (0,0)->(0,1)->(1,1)->(1,0);
// A-half read only when mh changes, BOTH B-halves held in regs.
// XOR swizzle byte^=((row&7)<<4): pre-applied to per-lane global src
// (gl_lds dest linear), applied again on ds_read side.
// vmcnt(4|3) only at phases 4 and 8 (counted, never drained in-loop).
template <int BN, int MW, int EPI>
__global__ __launch_bounds__(512) void gemm8(const u16* __restrict__ A,
                                             const u16* __restrict__ Bt,
                                             void* __restrict__ Cv,
                                             const float* __restrict__ bias,
                                             int N, int Kd) {
    extern __shared__ char smem[];
    constexpr int BHB = (BN == 256) ? 16384 : 8192;  // B half bytes
    constexpr int BROWS = BN / 2;                    // B half rows
    constexpr int NW = 8 / MW;                       // waves along N
    constexpr int MF = 128 / (16 * MW);              // A frags per wave per half
    constexpr int MROW = 128 / MW;                   // wave row stride within half
    char* ldsA = smem;                // 4 halves * 16KB
    char* ldsB = smem + 65536;        // 4 halves * BHB

    const int tid = threadIdx.x;
    const int l = tid & 63;
    const int wv = tid >> 6;
    const int wr = wv / NW;
    const int wc = wv % NW;

    int bid = blockIdx.x;            // 256 blocks always
    bid = (bid & 7) * 32 + (bid >> 3);   // bijective XCD swizzle (256%8==0)
    const int mt = bid >> 4, nt = bid & 15;
    const int m0 = mt * 256, n0 = nt * BN;

    const int NITER = Kd >> 7;

    // staging per-thread source offsets (swizzle pre-applied to global src)
    size_t aoff[2], boff[2];
    {
        #pragma unroll
        for (int r = 0; r < 2; ++r) {
            int lin = (r * 512 + tid) * 16;
            int s = lin ^ (((lin >> 7) & 7) << 4);
            int e = s >> 1;
            size_t o = (size_t)(e >> 6) * Kd + (e & 63);
            aoff[r] = (size_t)m0 * Kd + o;
            boff[r] = (size_t)n0 * Kd + o;
        }
    }

    auto issueA = [&](int h, int b, size_t kb) {
        char* d = ldsA + (((b << 1) | h) * 16384) + tid * 16;
        gl_lds16(A + aoff[0] + (size_t)h * 128 * Kd + kb, d);
        gl_lds16(A + aoff[1] + (size_t)h * 128 * Kd + kb, d + 8192);
    };
    auto issueB = [&](int h, int b, size_t kb) {
        char* d = ldsB + (((b << 1) | h) * BHB) + tid * 16;
        gl_lds16(Bt + boff[0] + (size_t)h * BROWS * Kd + kb, d);
        if constexpr (BN == 256)
            gl_lds16(Bt + boff[1] + (size_t)h * BROWS * Kd + kb, d + 8192);
    };

    // LDS read addr = row*128 | cc0 (second k-slice: ^64); cc0 folds the swizzle
    int rowAb[MF];
    #pragma unroll
    for (int m = 0; m < MF; ++m) rowAb[m] = (wr * MROW + m * 16 + (l & 15)) * 128;
    int rowBb[2];
    #pragma unroll
    for (int n = 0; n < 2; ++n) rowBb[n] = (wc * 32 + n * 16 + (l & 15)) * 128;
    const int cc0 = ((l >> 4) ^ (l & 7)) << 4;

    f32x4 acc[2][2][MF][2] = {};
    bf16x8 af[MF][2];        // A frags, current mh
    bf16x8 bf[2][2][2];      // B frags, BOTH nh halves held

#define PHASE(BUF, MH, NH, RDA, RDB, ISSUE_STMT, VM) do {                         \
    const char* Ah_ = ldsA + (((BUF) << 1) | (MH)) * 16384;                       \
    const char* Bh_ = ldsB + (((BUF) << 1) | (NH)) * BHB;                         \
    if (RDA) { _Pragma("unroll") for (int m_ = 0; m_ < MF; ++m_) {                \
        af[m_][0] = *(const bf16x8*)(Ah_ + (rowAb[m_] | cc0));                    \
        af[m_][1] = *(const bf16x8*)(Ah_ + ((rowAb[m_] | cc0) ^ 64)); } }         \
    if (RDB) { _Pragma("unroll") for (int n_ = 0; n_ < 2; ++n_) {                 \
        bf[NH][n_][0] = *(const bf16x8*)(Bh_ + (rowBb[n_] | cc0));                \
        bf[NH][n_][1] = *(const bf16x8*)(Bh_ + ((rowBb[n_] | cc0) ^ 64)); } }     \
    ISSUE_STMT;                                                                   \
    __builtin_amdgcn_s_barrier();                                                 \
    asm volatile("s_waitcnt lgkmcnt(0)" ::: "memory");                            \
    __builtin_amdgcn_s_setprio(1);                                                \
    _Pragma("unroll") for (int m_ = 0; m_ < MF; ++m_)                             \
        _Pragma("unroll") for (int n_ = 0; n_ < 2; ++n_) {                        \
            acc[MH][NH][m_][n_] = __builtin_amdgcn_mfma_f32_16x16x32_bf16(        \
                af[m_][0], bf[NH][n_][0], acc[MH][NH][m_][n_], 0, 0, 0);          \
            acc[MH][NH][m_][n_] = __builtin_amdgcn_mfma_f32_16x16x32_bf16(        \
                af[m_][1], bf[NH][n_][1], acc[MH][NH][m_][n_], 0, 0, 0); }        \
    __builtin_amdgcn_s_setprio(0);                                                \
    if (VM) { if (BN == 256) asm volatile("s_waitcnt vmcnt(4)" ::: "memory");     \
              else           asm volatile("s_waitcnt vmcnt(3)" ::: "memory"); }   \
    __builtin_amdgcn_s_barrier();                                                 \
} while (0)

    // prologue: tile0 all 4 halves + tile1 {A0,B0}; keep tile1 pair in flight
    issueA(0, 0, 0);  issueB(0, 0, 0);
    issueA(1, 0, 0);  issueB(1, 0, 0);
    issueA(0, 1, 64); issueB(0, 1, 64);
    if (BN == 256) asm volatile("s_waitcnt vmcnt(4)" ::: "memory");
    else           asm volatile("s_waitcnt vmcnt(3)" ::: "memory");
    __builtin_amdgcn_s_barrier();

    for (int J = 0; J < NITER; ++J) {
        const size_t kc = (size_t)J << 7;
        PHASE(0, 0, 0, 1, 1, issueA(1, 1, kc + 64),  0);
        PHASE(0, 0, 1, 0, 1, issueB(1, 1, kc + 64),  0);
        PHASE(0, 1, 1, 1, 0, issueA(0, 0, kc + 128), 0);
        PHASE(0, 1, 0, 0, 0, issueB(0, 0, kc + 128), 1);
        PHASE(1, 0, 0, 1, 1, issueA(1, 0, kc + 128), 0);
        PHASE(1, 0, 1, 0, 1, issueB(1, 0, kc + 128), 0);
        PHASE(1, 1, 1, 1, 0, issueA(0, 1, kc + 192), 0);
        PHASE(1, 1, 0, 0, 0, issueB(0, 1, kc + 192), 1);
    }
#undef PHASE

    const int colc = l & 15, rb = (l >> 4) * 4;
    #pragma unroll
    for (int mh = 0; mh < 2; ++mh)
    #pragma unroll
    for (int nh = 0; nh < 2; ++nh)
    #pragma unroll
    for (int m = 0; m < MF; ++m)
    #pragma unroll
    for (int n = 0; n < 2; ++n) {
        int c = n0 + nh * (BN / 2) + wc * 32 + n * 16 + colc;
        int r0r = m0 + mh * 128 + wr * MROW + m * 16 + rb;
        if (EPI == 0) {
            u16* Cb = (u16*)Cv;
            #pragma unroll
            for (int j = 0; j < 4; ++j)
                Cb[(size_t)(r0r + j) * N + c] = f2bf(acc[mh][nh][m][n][j]);
        } else {
            float* Cf = (float*)Cv;
            float bv = bias[c];
            #pragma unroll
            for (int j = 0; j < 4; ++j)
                Cf[(size_t)(r0r + j) * N + c] = (acc[mh][nh][m][n][j] + bv) * 0.125f;
        }
    }
}

extern "C" void kernel_launch(void* const* d_in, const int* in_sizes, int n_in,
                              void* d_out, int out_size, void* d_ws, size_t ws_size,
                              hipStream_t stream) {
    const float* hin  = (const float*)d_in[0];
    const float* S1s  = (const float*)d_in[1];
    const float* S2s  = (const float*)d_in[2];
    const float* U1s  = (const float*)d_in[3];
    const float* U2s  = (const float*)d_in[4];
    const float* bias = (const float*)d_in[5];
    float* out = (float*)d_out;

    // ws: [hinbf][Wx (W1T then W2T)][abf], each padded 512B for the last
    // iteration's prefetch overread (<=256B past the K extent).
    const size_t SZ_HIN = (size_t)BB * DIN * 2 + 512;
    const size_t SZ_W   = (size_t)RK * DIN * 2 + 512;
    const size_t SZ_A   = (size_t)BB * RK * 2 + 512;
    if (ws_size < SZ_HIN + SZ_W + SZ_A) return;
    u16* hinbf = (u16*)d_ws;
    u16* Wx    = (u16*)((char*)d_ws + SZ_HIN);
    u16* abf   = (u16*)((char*)d_ws + SZ_HIN + SZ_W);

    (void)hipFuncSetAttribute(reinterpret_cast<const void*>(&gemm8<128, 4, 0>),
                              hipFuncAttributeMaxDynamicSharedMemorySize, 98304);
    (void)hipFuncSetAttribute(reinterpret_cast<const void*>(&gemm8<256, 2, 1>),
                              hipFuncAttributeMaxDynamicSharedMemorySize, 131072);

    // 1) pack W1T [RK][DIN]; hin -> bf16
    pack_w1t<<<64 * 4 * 8, 256, 0, stream>>>(S1s, U2s, Wx);
    cvt_f32_bf16<<<(BB * DIN / 8) / 256, 256, 0, stream>>>(hin, hinbf, BB * DIN / 8);
    // 2) a[b][r] = sum_d hin[b][d] * W1T[r][d]   (M=4096, N=2048, K=4096; 64x64 waves)
    gemm8<128, 4, 0><<<256, 512, 98304, stream>>>(hinbf, Wx, abf, nullptr, RK, DIN);
    // 3) pack W2T [DOUT][RK] (reuses Wx after gemm1)
    pack_w2t<<<64 * 4 * 8, 256, 0, stream>>>(U1s, S2s, Wx);
    // 4) out = (a @ W2T^T + bias) / 8   (M=4096, N=4096, K=2048; 128x64 waves)
    gemm8<256, 2, 1><<<256, 512, 131072, stream>>>(abf, Wx, out, bias, DOUT, RK);
}

// Round 6
// 166.126 us; speedup vs baseline: 2.1034x; 1.0182x over previous
//
#include <hip/hip_runtime.h>
#include <stdint.h>

typedef unsigned short u16;
typedef __bf16 bf16x8 __attribute__((ext_vector_type(8)));
typedef float f32x4 __attribute__((ext_vector_type(4)));

#define DIN 4096
#define DOUT 4096
#define BB 4096
#define KR 256
#define RK 2048  // 2*L*K

__device__ __forceinline__ u16 f2bf(float f) {
    union { float f; unsigned u; } v; v.f = f;
    unsigned r = v.u + 0x7FFFu + ((v.u >> 16) & 1u);
    return (u16)(r >> 16);
}

__device__ __forceinline__ void gl_lds16(const void* g, void* l) {
    __builtin_amdgcn_global_load_lds((const __attribute__((address_space(1))) void*)g,
                                     (__attribute__((address_space(3))) void*)l,
                                     16, 0, 0);
}

// ---- convert f32 -> bf16, 8 elements/thread ----
__global__ __launch_bounds__(256) void cvt_f32_bf16(const float* __restrict__ src,
                                                    u16* __restrict__ dst, int n8) {
    int i = blockIdx.x * blockDim.x + threadIdx.x;
    if (i >= n8) return;
    const float4* s = reinterpret_cast<const float4*>(src) + (size_t)i * 2;
    float4 a = s[0], b = s[1];
    uint4 o;
    o.x = f2bf(a.x) | ((unsigned)f2bf(a.y) << 16);
    o.y = f2bf(a.z) | ((unsigned)f2bf(a.w) << 16);
    o.z = f2bf(b.x) | ((unsigned)f2bf(b.y) << 16);
    o.w = f2bf(b.z) | ((unsigned)f2bf(b.w) << 16);
    reinterpret_cast<uint4*>(dst)[i] = o;
}

// ---- pack W1T[r][d] = (br? U2s : S1s)[l][d][k], r = l*512 + br*256 + k ----
__global__ __launch_bounds__(256) void pack_w1t(const float* __restrict__ S1s,
                                                const float* __restrict__ U2s,
                                                u16* __restrict__ W1T) {
    __shared__ u16 lds[64][68];
    int b  = blockIdx.x;
    int bd = b & 63;
    int bk = (b >> 6) & 3;
    int lb = b >> 8;
    int l = lb >> 1, br = lb & 1;
    const float* src = (br ? U2s : S1s) + (size_t)l * DIN * KR;
    int t = threadIdx.x;
    int d0 = bd * 64, k0 = bk * 64;
    int r0 = l * 512 + br * 256 + k0;
    #pragma unroll
    for (int p = 0; p < 4; ++p) {
        int dl = p * 16 + (t >> 4);
        int kc = (t & 15) * 4;
        float4 v = *reinterpret_cast<const float4*>(src + (size_t)(d0 + dl) * KR + k0 + kc);
        ushort4 pk;
        pk.x = f2bf(v.x); pk.y = f2bf(v.y); pk.z = f2bf(v.z); pk.w = f2bf(v.w);
        *reinterpret_cast<ushort4*>(&lds[dl][kc]) = pk;
    }
    __syncthreads();
    #pragma unroll
    for (int p = 0; p < 2; ++p) {
        int kl = p * 32 + (t >> 3);
        int d8 = t & 7;
        u16 tmp[8];
        #pragma unroll
        for (int j = 0; j < 8; ++j) tmp[j] = lds[d8 * 8 + j][kl];
        uint4 o;
        o.x = tmp[0] | ((unsigned)tmp[1] << 16);
        o.y = tmp[2] | ((unsigned)tmp[3] << 16);
        o.z = tmp[4] | ((unsigned)tmp[5] << 16);
        o.w = tmp[6] | ((unsigned)tmp[7] << 16);
        *reinterpret_cast<uint4*>(W1T + (size_t)(r0 + kl) * DIN + d0 + d8 * 8) = o;
    }
}

// ---- pack W2T[o][r] = (br? S2s : U1s)[l][k][o] ----
__global__ __launch_bounds__(256) void pack_w2t(const float* __restrict__ U1s,
                                                const float* __restrict__ S2s,
                                                u16* __restrict__ W2T) {
    __shared__ u16 lds[64][68];
    int b  = blockIdx.x;
    int bo = b & 63;
    int bk = (b >> 6) & 3;
    int lb = b >> 8;
    int l = lb >> 1, br = lb & 1;
    const float* src = (br ? S2s : U1s) + (size_t)l * KR * DOUT;
    int t = threadIdx.x;
    int o0 = bo * 64, k0 = bk * 64;
    #pragma unroll
    for (int p = 0; p < 4; ++p) {
        int kl = p * 16 + (t >> 4);
        int ol = (t & 15) * 4;
        float4 v = *reinterpret_cast<const float4*>(src + (size_t)(k0 + kl) * DOUT + o0 + ol);
        ushort4 pk;
        pk.x = f2bf(v.x); pk.y = f2bf(v.y); pk.z = f2bf(v.z); pk.w = f2bf(v.w);
        *reinterpret_cast<ushort4*>(&lds[kl][ol]) = pk;
    }
    __syncthreads();
    #pragma unroll
    for (int p = 0; p < 2; ++p) {
        int ol = p * 32 + (t >> 3);
        int k8 = t & 7;
        u16 tmp[8];
        #pragma unroll
        for (int j = 0; j < 8; ++j) tmp[j] = lds[k8 * 8 + j][ol];
        uint4 o;
        o.x = tmp[0] | ((unsigned)tmp[1] << 16);
        o.y = tmp[2] | ((unsigned)tmp[3] << 16);
        o.z = tmp[4] | ((unsigned)tmp[5] << 16);
        o.w = tmp[6] | ((unsigned)tmp[7] << 16);
        *reinterpret_cast<uint4*>(W2T + (size_t)(o0 + ol) * RK + l * 512 + br * 256 + k0 + k8 * 8) = o;
    }
}

// ==== 8-phase 256xBN GEMM: C[M][N] = A[M][Kd] * Bt[N][Kd]^T ====
// BM=256, BK=64, 8 waves (MW x NW), 512 threads. 2 K-tiles/iter, 8 phases.
// SINGLE barrier per phase (end). Hazard proof: (a) WAR — each phase's
// gl_lds target slot is disjoint from that phase's AND the next phase's
// read slots; all reads of phase p are consumed by phase-p MFMAs, so
// they complete before the wave reaches barrier(p), and any write issued
// in p+1 happens after ALL waves passed barrier(p). (b) RAW — counted
// vmcnt at phases 4/8 (with "memory" fence) gates buffer readiness.
// No forced lgkmcnt(0): compiler emits counted per-use lgkm waits, so
// ds_reads overlap MFMA within a wave, and waves desync within a phase
// so LDS and MFMA pipes overlap across waves.
template <int BN, int MW, int EPI>
__global__ __launch_bounds__(512) void gemm8(const u16* __restrict__ A,
                                             const u16* __restrict__ Bt,
                                             void* __restrict__ Cv,
                                             const float* __restrict__ bias,
                                             int N, int Kd) {
    extern __shared__ char smem[];
    constexpr int BHB = (BN == 256) ? 16384 : 8192;  // B half bytes
    constexpr int BROWS = BN / 2;                    // B half rows
    constexpr int NW = 8 / MW;                       // waves along N
    constexpr int MF = 128 / (16 * MW);              // A frags per wave per half
    constexpr int MROW = 128 / MW;                   // wave row stride within half
    char* ldsA = smem;                // 4 halves * 16KB
    char* ldsB = smem + 65536;        // 4 halves * BHB

    const int tid = threadIdx.x;
    const int l = tid & 63;
    const int wv = tid >> 6;
    const int wr = wv / NW;
    const int wc = wv % NW;

    int bid = blockIdx.x;            // 256 blocks always
    bid = (bid & 7) * 32 + (bid >> 3);   // bijective XCD swizzle (256%8==0)
    const int mt = bid >> 4, nt = bid & 15;
    const int m0 = mt * 256, n0 = nt * BN;

    const int NITER = Kd >> 7;

    // staging per-thread source offsets (swizzle pre-applied to global src)
    size_t aoff[2], boff[2];
    {
        #pragma unroll
        for (int r = 0; r < 2; ++r) {
            int lin = (r * 512 + tid) * 16;
            int s = lin ^ (((lin >> 7) & 7) << 4);
            int e = s >> 1;
            size_t o = (size_t)(e >> 6) * Kd + (e & 63);
            aoff[r] = (size_t)m0 * Kd + o;
            boff[r] = (size_t)n0 * Kd + o;
        }
    }

    auto issueA = [&](int h, int b, size_t kb) {
        char* d = ldsA + (((b << 1) | h) * 16384) + tid * 16;
        gl_lds16(A + aoff[0] + (size_t)h * 128 * Kd + kb, d);
        gl_lds16(A + aoff[1] + (size_t)h * 128 * Kd + kb, d + 8192);
    };
    auto issueB = [&](int h, int b, size_t kb) {
        char* d = ldsB + (((b << 1) | h) * BHB) + tid * 16;
        gl_lds16(Bt + boff[0] + (size_t)h * BROWS * Kd + kb, d);
        if constexpr (BN == 256)
            gl_lds16(Bt + boff[1] + (size_t)h * BROWS * Kd + kb, d + 8192);
    };

    // LDS read addr = row*128 | cc0 (second k-slice: ^64); cc0 folds the swizzle
    int rowAb[MF];
    #pragma unroll
    for (int m = 0; m < MF; ++m) rowAb[m] = (wr * MROW + m * 16 + (l & 15)) * 128;
    int rowBb[2];
    #pragma unroll
    for (int n = 0; n < 2; ++n) rowBb[n] = (wc * 32 + n * 16 + (l & 15)) * 128;
    const int cc0 = ((l >> 4) ^ (l & 7)) << 4;

    f32x4 acc[2][2][MF][2] = {};
    bf16x8 af[MF][2];        // A frags, current mh
    bf16x8 bf[2][2][2];      // B frags, BOTH nh halves held

#define PHASE(BUF, MH, NH, RDA, RDB, ISSUE_STMT, VM) do {                         \
    ISSUE_STMT;                                                                   \
    const char* Ah_ = ldsA + (((BUF) << 1) | (MH)) * 16384;                       \
    const char* Bh_ = ldsB + (((BUF) << 1) | (NH)) * BHB;                         \
    if (RDA) { _Pragma("unroll") for (int m_ = 0; m_ < MF; ++m_) {                \
        af[m_][0] = *(const bf16x8*)(Ah_ + (rowAb[m_] | cc0));                    \
        af[m_][1] = *(const bf16x8*)(Ah_ + ((rowAb[m_] | cc0) ^ 64)); } }         \
    if (RDB) { _Pragma("unroll") for (int n_ = 0; n_ < 2; ++n_) {                 \
        bf[NH][n_][0] = *(const bf16x8*)(Bh_ + (rowBb[n_] | cc0));                \
        bf[NH][n_][1] = *(const bf16x8*)(Bh_ + ((rowBb[n_] | cc0) ^ 64)); } }     \
    __builtin_amdgcn_s_setprio(1);                                                \
    _Pragma("unroll") for (int m_ = 0; m_ < MF; ++m_)                             \
        _Pragma("unroll") for (int n_ = 0; n_ < 2; ++n_) {                        \
            acc[MH][NH][m_][n_] = __builtin_amdgcn_mfma_f32_16x16x32_bf16(        \
                af[m_][0], bf[NH][n_][0], acc[MH][NH][m_][n_], 0, 0, 0);          \
            acc[MH][NH][m_][n_] = __builtin_amdgcn_mfma_f32_16x16x32_bf16(        \
                af[m_][1], bf[NH][n_][1], acc[MH][NH][m_][n_], 0, 0, 0); }        \
    __builtin_amdgcn_s_setprio(0);                                                \
    if (VM) { if (BN == 256) asm volatile("s_waitcnt vmcnt(4)" ::: "memory");     \
              else           asm volatile("s_waitcnt vmcnt(3)" ::: "memory"); }   \
    asm volatile("" ::: "memory");                                                \
    __builtin_amdgcn_s_barrier();                                                 \
} while (0)

    // prologue: tile0 all 4 halves + tile1 {A0,B0}; keep tile1 pair in flight
    issueA(0, 0, 0);  issueB(0, 0, 0);
    issueA(1, 0, 0);  issueB(1, 0, 0);
    issueA(0, 1, 64); issueB(0, 1, 64);
    if (BN == 256) asm volatile("s_waitcnt vmcnt(4)" ::: "memory");
    else           asm volatile("s_waitcnt vmcnt(3)" ::: "memory");
    __builtin_amdgcn_s_barrier();

    for (int J = 0; J < NITER; ++J) {
        const size_t kc = (size_t)J << 7;
        PHASE(0, 0, 0, 1, 1, issueA(1, 1, kc + 64),  0);
        PHASE(0, 0, 1, 0, 1, issueB(1, 1, kc + 64),  0);
        PHASE(0, 1, 1, 1, 0, issueA(0, 0, kc + 128), 0);
        PHASE(0, 1, 0, 0, 0, issueB(0, 0, kc + 128), 1);
        PHASE(1, 0, 0, 1, 1, issueA(1, 0, kc + 128), 0);
        PHASE(1, 0, 1, 0, 1, issueB(1, 0, kc + 128), 0);
        PHASE(1, 1, 1, 1, 0, issueA(0, 1, kc + 192), 0);
        PHASE(1, 1, 0, 0, 0, issueB(0, 1, kc + 192), 1);
    }
#undef PHASE

    const int colc = l & 15, rb = (l >> 4) * 4;
    #pragma unroll
    for (int mh = 0; mh < 2; ++mh)
    #pragma unroll
    for (int nh = 0; nh < 2; ++nh)
    #pragma unroll
    for (int m = 0; m < MF; ++m)
    #pragma unroll
    for (int n = 0; n < 2; ++n) {
        int c = n0 + nh * (BN / 2) + wc * 32 + n * 16 + colc;
        int r0r = m0 + mh * 128 + wr * MROW + m * 16 + rb;
        if (EPI == 0) {
            u16* Cb = (u16*)Cv;
            #pragma unroll
            for (int j = 0; j < 4; ++j)
                Cb[(size_t)(r0r + j) * N + c] = f2bf(acc[mh][nh][m][n][j]);
        } else {
            float* Cf = (float*)Cv;
            float bv = bias[c];
            #pragma unroll
            for (int j = 0; j < 4; ++j)
                Cf[(size_t)(r0r + j) * N + c] = (acc[mh][nh][m][n][j] + bv) * 0.125f;
        }
    }
}

extern "C" void kernel_launch(void* const* d_in, const int* in_sizes, int n_in,
                              void* d_out, int out_size, void* d_ws, size_t ws_size,
                              hipStream_t stream) {
    const float* hin  = (const float*)d_in[0];
    const float* S1s  = (const float*)d_in[1];
    const float* S2s  = (const float*)d_in[2];
    const float* U1s  = (const float*)d_in[3];
    const float* U2s  = (const float*)d_in[4];
    const float* bias = (const float*)d_in[5];
    float* out = (float*)d_out;

    // ws: [hinbf][Wx (W1T then W2T)][abf], each padded 512B for the last
    // iteration's prefetch overread (<=256B past the K extent).
    const size_t SZ_HIN = (size_t)BB * DIN * 2 + 512;
    const size_t SZ_W   = (size_t)RK * DIN * 2 + 512;
    const size_t SZ_A   = (size_t)BB * RK * 2 + 512;
    if (ws_size < SZ_HIN + SZ_W + SZ_A) return;
    u16* hinbf = (u16*)d_ws;
    u16* Wx    = (u16*)((char*)d_ws + SZ_HIN);
    u16* abf   = (u16*)((char*)d_ws + SZ_HIN + SZ_W);

    (void)hipFuncSetAttribute(reinterpret_cast<const void*>(&gemm8<128, 4, 0>),
                              hipFuncAttributeMaxDynamicSharedMemorySize, 98304);
    (void)hipFuncSetAttribute(reinterpret_cast<const void*>(&gemm8<256, 2, 1>),
                              hipFuncAttributeMaxDynamicSharedMemorySize, 131072);

    // 1) pack W1T [RK][DIN]; hin -> bf16
    pack_w1t<<<64 * 4 * 8, 256, 0, stream>>>(S1s, U2s, Wx);
    cvt_f32_bf16<<<(BB * DIN / 8) / 256, 256, 0, stream>>>(hin, hinbf, BB * DIN / 8);
    // 2) a[b][r] = sum_d hin[b][d] * W1T[r][d]   (M=4096, N=2048, K=4096; 64x64 waves)
    gemm8<128, 4, 0><<<256, 512, 98304, stream>>>(hinbf, Wx, abf, nullptr, RK, DIN);
    // 3) pack W2T [DOUT][RK] (reuses Wx after gemm1)
    pack_w2t<<<64 * 4 * 8, 256, 0, stream>>>(U1s, S2s, Wx);
    // 4) out = (a @ W2T^T + bias) / 8   (M=4096, N=4096, K=2048; 128x64 waves)
    gemm8<256, 2, 1><<<256, 512, 131072, stream>>>(abf, Wx, out, bias, DOUT, RK);
}